// Round 1
// baseline (85.439 us; speedup 1.0000x reference)
//
#include <hip/hip_runtime.h>
#include <math.h>

#define NN 207
#define BB 2
#define TT 864
#define LL 12
#define DD 96
#define PP 72
#define EPSF 1e-8f

__global__ __launch_bounds__(256) void stpe_fused_kernel(
    const float* __restrict__ x,      // (B,N,1,T)
    const float* __restrict__ adj,    // (N,N)
    const float* __restrict__ noise,  // (N,N)
    const float* __restrict__ W,      // (D,N,L)
    const float* __restrict__ bias,   // (D,)
    const int*   __restrict__ kptr,   // scalar k
    float*       __restrict__ out)    // (B,N,D,P)
{
    __shared__ float s_score[NN];
    __shared__ float s_x[TT];
    __shared__ float s_weff[DD * LL];
    __shared__ float s_topS[32];
    __shared__ int   s_topI[32];
    __shared__ float s_m, s_sum;

    const int blk = blockIdx.x;
    const int b   = blk / NN;
    const int i   = blk - b * NN;
    const int tid = threadIdx.x;
    const int kk  = min(*kptr, 32);

    // 1. Gumbel-perturbed logits for row i (TAU == 1 so no divide)
    if (tid < NN) {
        float a = fmaxf(adj[i * NN + tid], 0.0f) + EPSF;
        float u = noise[i * NN + tid] + EPSF;
        float g = -logf(-logf(u));
        s_score[tid] = logf(a) + g;
    }
    // co-load x row for this (b,i)
    for (int t = tid; t < TT; t += 256) s_x[t] = x[(b * NN + i) * TT + t];
    __syncthreads();

    // 2. wave 0: top-k extraction + softmax stats
    if (tid < 64) {
        const int lane = tid;
        float v[4], orig[4];
        #pragma unroll
        for (int q = 0; q < 4; ++q) {
            int c = lane + 64 * q;
            v[q] = (c < NN) ? s_score[c] : -INFINITY;
            orig[q] = v[q];
        }
        float m = 0.0f;
        for (int it = 0; it < kk; ++it) {
            float bv = v[0]; int bi = lane;
            #pragma unroll
            for (int q = 1; q < 4; ++q)
                if (v[q] > bv) { bv = v[q]; bi = lane + 64 * q; }
            #pragma unroll
            for (int off = 32; off > 0; off >>= 1) {
                float ov = __shfl_xor(bv, off);
                int   oi = __shfl_xor(bi, off);
                if (ov > bv || (ov == bv && oi < bi)) { bv = ov; bi = oi; }
            }
            if (it == 0) m = bv;                       // softmax max = top-1
            if (lane == 0) { s_topS[it] = bv; s_topI[it] = bi; }
            if ((bi & 63) == lane) v[bi >> 6] = -INFINITY;  // remove winner
        }
        float se = 0.0f;
        #pragma unroll
        for (int q = 0; q < 4; ++q) {
            int c = lane + 64 * q;
            if (c < NN) se += expf(orig[q] - m);
        }
        #pragma unroll
        for (int off = 32; off > 0; off >>= 1) se += __shfl_xor(se, off);
        if (lane == 0) { s_m = m; s_sum = se; }
    }
    __syncthreads();

    // 3. convert top-k scores to softmax probabilities (the mask values)
    if (tid < kk) s_topS[tid] = expf(s_topS[tid] - s_m) / s_sum;
    __syncthreads();

    // 4. Weff[d][l] = sum_t mask_val[t] * W[d, idx[t], l]
    for (int e = tid; e < DD * LL; e += 256) {
        int d = e / LL, l = e - d * LL;
        float acc = 0.0f;
        for (int t = 0; t < kk; ++t)
            acc += s_topS[t] * W[(d * NN + s_topI[t]) * LL + l];
        s_weff[e] = acc;
    }
    __syncthreads();

    // 5. out[b,i,d,p] = bias[d] + sum_l x[p*L+l] * Weff[d,l]
    for (int e = tid; e < DD * PP; e += 256) {
        int d = e / PP, p = e - d * PP;
        float acc = bias[d];
        const float* xr = &s_x[p * LL];
        const float* wr = &s_weff[d * LL];
        #pragma unroll
        for (int l = 0; l < LL; ++l) acc += xr[l] * wr[l];
        out[((b * NN + i) * DD + d) * PP + p] = acc;
    }
}

extern "C" void kernel_launch(void* const* d_in, const int* in_sizes, int n_in,
                              void* d_out, int out_size, void* d_ws, size_t ws_size,
                              hipStream_t stream) {
    const float* x     = (const float*)d_in[0];  // long_term_history (B,N,1,T)
    const float* adj   = (const float*)d_in[1];  // (N,N)
    const float* noise = (const float*)d_in[2];  // (N,N)
    const float* W     = (const float*)d_in[3];  // (D,N,L)
    const float* bias  = (const float*)d_in[4];  // (D,)
    const int*   kptr  = (const int*)d_in[5];    // scalar k
    float* out = (float*)d_out;

    stpe_fused_kernel<<<BB * NN, 256, 0, stream>>>(x, adj, noise, W, bias, kptr, out);
}

// Round 2
// 83.966 us; speedup vs baseline: 1.0175x; 1.0175x over previous
//
#include <hip/hip_runtime.h>
#include <math.h>

#define NN 207
#define BB 2
#define TT 864
#define LL 12
#define DD 96
#define PP 72
#define EPSF 1e-8f

__global__ __launch_bounds__(256) void stpe_fused_kernel(
    const float* __restrict__ x,      // (B,N,1,T)
    const float* __restrict__ adj,    // (N,N)
    const float* __restrict__ noise,  // (N,N)
    const float* __restrict__ W,      // (D,N,L)
    const float* __restrict__ bias,   // (D,)
    const int*   __restrict__ kptr,   // scalar k
    float*       __restrict__ out)    // (B,N,D,P)
{
    __shared__ float s_score[NN];
    __shared__ float s_x[BB][TT];
    __shared__ float s_weff[DD * LL];
    __shared__ float s_bias[DD];
    __shared__ float s_topS[32];
    __shared__ int   s_topI[32];

    const int i   = blockIdx.x;      // graph row
    const int tid = threadIdx.x;
    const int kk  = min(*kptr, 32);

    // ---- Phase 1: Gumbel scores for row i; stage x (both batches) + bias ----
    if (tid < NN) {
        float a = fmaxf(adj[i * NN + tid], 0.0f) + EPSF;
        float u = noise[i * NN + tid] + EPSF;
        s_score[tid] = logf(a) - logf(-logf(u));
    }
    if (tid < DD) s_bias[tid] = bias[tid];

    // x rows for b=0,1: each 864 floats = 216 float4, 48B-row-aligned
    {
        const float4* x4  = (const float4*)x;
        float4*       sx4 = (float4*)&s_x[0][0];
        for (int q = tid; q < BB * (TT / 4); q += 256) {
            int b = q / (TT / 4), r = q - b * (TT / 4);
            sx4[q] = x4[(b * NN + i) * (TT / 4) + r];
        }
    }
    __syncthreads();

    // ---- Phase 2: wave 0 does top-k + softmax; writes final probs ----
    if (tid < 64) {
        const int lane = tid;
        float v[4], orig[4];
        #pragma unroll
        for (int q = 0; q < 4; ++q) {
            int c = lane + 64 * q;
            v[q] = (c < NN) ? s_score[c] : -INFINITY;
            orig[q] = v[q];
        }
        float m = 0.0f, myv = 0.0f; int myi = 0;
        for (int it = 0; it < kk; ++it) {
            float bv = v[0]; int bi = lane;
            #pragma unroll
            for (int q = 1; q < 4; ++q)
                if (v[q] > bv) { bv = v[q]; bi = lane + 64 * q; }
            #pragma unroll
            for (int off = 32; off > 0; off >>= 1) {
                float ov = __shfl_xor(bv, off);
                int   oi = __shfl_xor(bi, off);
                if (ov > bv || (ov == bv && oi < bi)) { bv = ov; bi = oi; }
            }
            if (it == 0) m = bv;                     // softmax max = top-1
            if (lane == it) { myv = bv; myi = bi; }  // lane `it` owns winner `it`
            if ((bi & 63) == lane) v[bi >> 6] = -INFINITY;
        }
        float se = 0.0f;
        #pragma unroll
        for (int q = 0; q < 4; ++q) {
            int c = lane + 64 * q;
            if (c < NN) se += expf(orig[q] - m);
        }
        #pragma unroll
        for (int off = 32; off > 0; off >>= 1) se += __shfl_xor(se, off);
        if (lane < kk) {                             // se, m wave-uniform here
            s_topS[lane] = expf(myv - m) / se;
            s_topI[lane] = myi;
        }
    }
    __syncthreads();

    // ---- Phase 3: Weff[d][l] = sum_t prob[t] * W[d, idx[t], l] (float4) ----
    {
        const float4* W4 = (const float4*)W;       // (D*N) rows of 3 float4
        float4* weff4 = (float4*)s_weff;
        for (int e = tid; e < DD * 3; e += 256) {  // 288 float4 elems
            int d = e / 3, c = e - d * 3;
            float4 acc = {0.f, 0.f, 0.f, 0.f};
            for (int t = 0; t < kk; ++t) {
                float s  = s_topS[t];
                float4 w = W4[(d * NN + s_topI[t]) * 3 + c];
                acc.x += s * w.x; acc.y += s * w.y;
                acc.z += s * w.z; acc.w += s * w.w;
            }
            weff4[e] = acc;
        }
    }
    __syncthreads();

    // ---- Phase 4: out[b,i,d,p] = bias[d] + sum_l x[b,p*L+l]*Weff[d,l] ----
    // vectorized over p: 18 float4 per (b,d) row; 2*96*18 = 3456 float4
    {
        float4* out4 = (float4*)out;
        for (int e = tid; e < BB * DD * (PP / 4); e += 256) {
            int b = e / (DD * (PP / 4));
            int r = e - b * (DD * (PP / 4));
            int d = r / (PP / 4);
            int c = r - d * (PP / 4);
            int p0 = c * 4;
            const float* wr = &s_weff[d * LL];
            float bd = s_bias[d];
            float o[4];
            #pragma unroll
            for (int q = 0; q < 4; ++q) {
                const float* xr = &s_x[b][(p0 + q) * LL];
                float a = bd;
                #pragma unroll
                for (int l = 0; l < LL; ++l) a += xr[l] * wr[l];
                o[q] = a;
            }
            float4 val = {o[0], o[1], o[2], o[3]};
            out4[((b * NN + i) * DD + d) * (PP / 4) + c] = val;
        }
    }
}

extern "C" void kernel_launch(void* const* d_in, const int* in_sizes, int n_in,
                              void* d_out, int out_size, void* d_ws, size_t ws_size,
                              hipStream_t stream) {
    const float* x     = (const float*)d_in[0];
    const float* adj   = (const float*)d_in[1];
    const float* noise = (const float*)d_in[2];
    const float* W     = (const float*)d_in[3];
    const float* bias  = (const float*)d_in[4];
    const int*   kptr  = (const int*)d_in[5];
    float* out = (float*)d_out;

    stpe_fused_kernel<<<NN, 256, 0, stream>>>(x, adj, noise, W, bias, kptr, out);
}